// Round 1
// baseline (4569.209 us; speedup 1.0000x reference)
//
#include <hip/hip_runtime.h>

#define N_TOK 8192
#define DIM   2048
#define HID   8192
#define OUTD  2048
#define NEXP  8
#define SLOT_TILES 136
#define SLOT_CAP   (SLOT_TILES * 128)

typedef unsigned short u16;
typedef float v4f  __attribute__((ext_vector_type(4)));
typedef __bf16 v8bf __attribute__((ext_vector_type(8)));

// fp32 -> bf16 round-to-nearest-even (no NaN handling needed; data is finite)
__device__ inline u16 f2b(float f) {
    unsigned int u = __float_as_uint(f);
    u += 0x7fffu + ((u >> 16) & 1u);
    return (u16)(u >> 16);
}

// async global->LDS, 16B per lane; LDS dest = wave-uniform base + lane*16
__device__ inline void gll16(const void* g, void* l) {
    __builtin_amdgcn_global_load_lds(
        (__attribute__((address_space(1))) void*)g,
        (__attribute__((address_space(3))) void*)l, 16, 0, 0);
}

// ---------------------------------------------------------------- init
__global__ void k0_init(int* counts, int* cursor, float* P_acc, int* slot_token) {
    int i = blockIdx.x * 256 + threadIdx.x;
    if (i < NEXP) { counts[i] = 0; cursor[i] = 0; P_acc[i] = 0.f; }
    if (i < SLOT_CAP) slot_token[i] = -1;
}

// ---------------------------------------------------------------- router
// one wave per token: fp32 gate logits, softmax, top-2 (ties -> lower index),
// renormalized combine weights, expert counts, P accumulation for lb_loss
__global__ __launch_bounds__(256) void k1_router(
    const float* __restrict__ x, const float* __restrict__ gW,
    const float* __restrict__ gb, int* __restrict__ tok_e,
    float* __restrict__ tok_g, int* counts, float* P_acc)
{
    const int wv = threadIdx.x >> 6, lane = threadIdx.x & 63;
    const int t = blockIdx.x * 4 + wv;
    const float* xr = x + (size_t)t * DIM;
    float acc[NEXP];
#pragma unroll
    for (int e = 0; e < NEXP; e++) acc[e] = 0.f;
    for (int i = 0; i < DIM / 64; i++) {
        int k = i * 64 + lane;
        float xv = xr[k];
        const float* g = gW + (size_t)k * NEXP;
#pragma unroll
        for (int e = 0; e < NEXP; e++) acc[e] += xv * g[e];
    }
#pragma unroll
    for (int off = 32; off >= 1; off >>= 1)
#pragma unroll
        for (int e = 0; e < NEXP; e++) acc[e] += __shfl_xor(acc[e], off, 64);
    if (lane == 0) {
        float l[NEXP], mx = -1e30f;
#pragma unroll
        for (int e = 0; e < NEXP; e++) { l[e] = acc[e] + gb[e]; mx = fmaxf(mx, l[e]); }
        float p[NEXP], s = 0.f;
#pragma unroll
        for (int e = 0; e < NEXP; e++) { p[e] = __expf(l[e] - mx); s += p[e]; }
        float inv = 1.f / s;
#pragma unroll
        for (int e = 0; e < NEXP; e++) p[e] *= inv;
        int i0 = 0;
#pragma unroll
        for (int e = 1; e < NEXP; e++) if (p[e] > p[i0]) i0 = e;
        int i1 = (i0 == 0) ? 1 : 0;
#pragma unroll
        for (int e = 0; e < NEXP; e++) if (e != i0 && p[e] > p[i1]) i1 = e;
        float g0 = p[i0], g1 = p[i1], ss = 1.f / (g0 + g1);
        tok_e[2 * t] = i0; tok_e[2 * t + 1] = i1;
        tok_g[2 * t] = g0 * ss; tok_g[2 * t + 1] = g1 * ss;
        atomicAdd(&counts[i0], 1);
        atomicAdd(&counts[i1], 1);
#pragma unroll
        for (int e = 0; e < NEXP; e++) atomicAdd(&P_acc[e], p[e]);
    }
}

// ---------------------------------------------------------------- offsets + lb_loss
__global__ void k2_offsets(const int* counts, int* offs, int* mtile_expert,
                           const float* P_acc, float* lb_out) {
    if (threadIdx.x == 0) {
        int to = 0;
        for (int e = 0; e < NEXP; e++) {
            offs[e] = to * 128;
            int tiles = (counts[e] + 127) / 128;
            for (int j = 0; j < tiles; j++) mtile_expert[to + j] = e;
            to += tiles;
        }
        for (int j = to; j < SLOT_TILES; j++) mtile_expert[j] = -1;
        float lb = 0.f;
        for (int e = 0; e < NEXP; e++) {
            float pm = P_acc[e] / (float)N_TOK;
            lb += pm * pm;
        }
        lb_out[0] = lb * (float)NEXP;
    }
}

// ---------------------------------------------------------------- gather + convert x
// one block per token: claim 2 slots, copy x row as bf16 to both
__global__ __launch_bounds__(256) void k3_gather(
    const float* __restrict__ x, const int* __restrict__ tok_e,
    const float* __restrict__ tok_g, const int* __restrict__ offs,
    int* cursor, int* slot_token, float* slot_w, u16* __restrict__ xg)
{
    __shared__ int ss[2];
    const int t = blockIdx.x;
    if (threadIdx.x < 2) {
        int e = tok_e[2 * t + threadIdx.x];
        int s = offs[e] + atomicAdd(&cursor[e], 1);
        slot_token[s] = t;
        slot_w[s] = tok_g[2 * t + threadIdx.x];
        ss[threadIdx.x] = s;
    }
    __syncthreads();
    const int s0 = ss[0], s1 = ss[1];
    const float4* xr = (const float4*)(x + (size_t)t * DIM);
    u16* o0 = xg + (size_t)s0 * DIM;
    u16* o1 = xg + (size_t)s1 * DIM;
    for (int j = threadIdx.x; j < DIM / 4; j += 256) {
        float4 v = xr[j];
        ushort4 u;
        u.x = f2b(v.x); u.y = f2b(v.y); u.z = f2b(v.z); u.w = f2b(v.w);
        *(ushort4*)(o0 + (size_t)j * 4) = u;
        *(ushort4*)(o1 + (size_t)j * 4) = u;
    }
}

// ---------------------------------------------------------------- fp32 -> bf16 weight convert
__global__ void k_conv(const float4* __restrict__ in, ushort4* __restrict__ out, int n4) {
    int i = blockIdx.x * blockDim.x + threadIdx.x;
    int stride = gridDim.x * blockDim.x;
    for (; i < n4; i += stride) {
        float4 v = in[i];
        ushort4 u;
        u.x = f2b(v.x); u.y = f2b(v.y); u.z = f2b(v.z); u.w = f2b(v.w);
        out[i] = u;
    }
}

// ---------------------------------------------------------------- grouped GEMM
// 128x128 tile, BK=64, 4 waves (2x2), each wave 4x4 MFMA 16x16x32 frags.
// LDS tiles stored in MFMA-fragment order (chunk c = (mfg*2+ks)*64+lane, 16B each)
// so global_load_lds needs no padding and ds_read_b128 is conflict-free.
// A = slot-sorted rows (xg or h), B = per-expert weight rows, both K-contiguous.
template <bool IS_FC2>
__global__ __launch_bounds__(256) void moe_gemm(
    const u16* __restrict__ A, const u16* __restrict__ W,
    const float* __restrict__ bias, u16* __restrict__ Hout,
    float* __restrict__ Out, const int* __restrict__ mtile_expert,
    const int* __restrict__ slot_token, const float* __restrict__ slot_w,
    int K, int Ncols)
{
    __shared__ u16 sA[8192];
    __shared__ u16 sB[8192];
    const int nt = blockIdx.x, mt = blockIdx.y;
    const int e = mtile_expert[mt];
    if (e < 0) return;
    const int tid = threadIdx.x;
    const int lane = tid & 63;
    const int w = tid >> 6;
    const int wm = w >> 1, wn = w & 1;

    const u16* Ab = A + (size_t)mt * 128 * K;
    const u16* Bb = W + (size_t)e * Ncols * K + (size_t)nt * 128 * K;

    const u16* ag[4]; const u16* bg[4];
    u16* al[4]; u16* bl[4];
#pragma unroll
    for (int i = 0; i < 4; i++) {
        int cb = w * 4 + i;                       // chunk block 0..15
        int row = (cb >> 1) * 16 + (lane & 15);   // tile row 0..127
        int kk  = (cb & 1) * 32 + ((lane >> 4) << 3);
        ag[i] = Ab + (size_t)row * K + kk;
        bg[i] = Bb + (size_t)row * K + kk;
        al[i] = &sA[cb * 512];
        bl[i] = &sB[cb * 512];
    }

    v4f zero = {0.f, 0.f, 0.f, 0.f};
    v4f acc[4][4];
#pragma unroll
    for (int i = 0; i < 4; i++)
#pragma unroll
        for (int j = 0; j < 4; j++) acc[i][j] = zero;

    for (int k0 = 0; k0 < K; k0 += 64) {
        __syncthreads();
#pragma unroll
        for (int i = 0; i < 4; i++) { gll16(ag[i], al[i]); ag[i] += 64; }
#pragma unroll
        for (int i = 0; i < 4; i++) { gll16(bg[i], bl[i]); bg[i] += 64; }
        __syncthreads();
#pragma unroll
        for (int ks = 0; ks < 2; ks++) {
            v8bf af[4], bfr[4];
#pragma unroll
            for (int f = 0; f < 4; f++) {
                af[f]  = *(const v8bf*)&sA[(size_t)(((wm * 4 + f) * 2 + ks) * 64 + lane) * 8];
                bfr[f] = *(const v8bf*)&sB[(size_t)(((wn * 4 + f) * 2 + ks) * 64 + lane) * 8];
            }
#pragma unroll
            for (int mf = 0; mf < 4; mf++)
#pragma unroll
                for (int nf = 0; nf < 4; nf++)
                    acc[mf][nf] = __builtin_amdgcn_mfma_f32_16x16x32_bf16(
                        af[mf], bfr[nf], acc[mf][nf], 0, 0, 0);
        }
    }

    // D frag: col(n) = lane&15, row(m) = (lane>>4)*4 + reg
    const int r0 = (lane >> 4) * 4;
    const int c0 = lane & 15;
    if (!IS_FC2) {
#pragma unroll
        for (int nf = 0; nf < 4; nf++) {
            int gcol = nt * 128 + wn * 64 + nf * 16 + c0;
            float bb = bias[(size_t)e * Ncols + gcol];
#pragma unroll
            for (int mf = 0; mf < 4; mf++)
#pragma unroll
                for (int r = 0; r < 4; r++) {
                    int grow = mt * 128 + wm * 64 + mf * 16 + r0 + r;
                    float v = acc[mf][nf][r] + bb;
                    v = v > 0.f ? v : 0.f;
                    Hout[(size_t)grow * Ncols + gcol] = f2b(v);
                }
        }
    } else {
#pragma unroll
        for (int mf = 0; mf < 4; mf++)
#pragma unroll
            for (int r = 0; r < 4; r++) {
                int srow = mt * 128 + wm * 64 + mf * 16 + r0 + r;
                int tok = slot_token[srow];
                if (tok < 0) continue;
                float wgt = slot_w[srow];
#pragma unroll
                for (int nf = 0; nf < 4; nf++) {
                    int gcol = nt * 128 + wn * 64 + nf * 16 + c0;
                    float bb = bias[(size_t)e * Ncols + gcol];
                    atomicAdd(&Out[(size_t)tok * OUTD + gcol], wgt * (acc[mf][nf][r] + bb));
                }
            }
    }
}

// ---------------------------------------------------------------- launch
extern "C" void kernel_launch(void* const* d_in, const int* in_sizes, int n_in,
                              void* d_out, int out_size, void* d_ws, size_t ws_size,
                              hipStream_t stream) {
    const float* x  = (const float*)d_in[0];
    const float* gW = (const float*)d_in[1];
    const float* gb = (const float*)d_in[2];
    const float* W1 = (const float*)d_in[3];
    const float* b1 = (const float*)d_in[4];
    const float* W2 = (const float*)d_in[5];
    const float* b2 = (const float*)d_in[6];
    float* out = (float*)d_out;

    // workspace carve (same every call). Total ~625 MB.
    char* p = (char*)d_ws;
    auto carve = [&](size_t bytes) {
        char* r = p;
        p += (bytes + 255) & ~(size_t)255;
        return (void*)r;
    };
    int*   counts     = (int*)carve(NEXP * 4);
    int*   cursor     = (int*)carve(NEXP * 4);
    float* P_acc      = (float*)carve(NEXP * 4);
    int*   offs       = (int*)carve(NEXP * 4);
    int*   mtile_e    = (int*)carve(SLOT_TILES * 4);
    int*   tok_e      = (int*)carve((size_t)N_TOK * 2 * 4);
    float* tok_g      = (float*)carve((size_t)N_TOK * 2 * 4);
    int*   slot_token = (int*)carve((size_t)SLOT_CAP * 4);
    float* slot_w     = (float*)carve((size_t)SLOT_CAP * 4);
    u16*   xg         = (u16*)carve((size_t)SLOT_CAP * DIM * 2);
    u16*   Wbuf       = (u16*)carve((size_t)NEXP * HID * DIM * 2);   // reused for W2
    u16*   h          = (u16*)carve((size_t)SLOT_CAP * HID * 2);

    (void)hipMemsetAsync(d_out, 0, (size_t)N_TOK * OUTD * sizeof(float), stream);
    k0_init<<<dim3(SLOT_CAP / 256), dim3(256), 0, stream>>>(counts, cursor, P_acc, slot_token);
    k1_router<<<dim3(N_TOK / 4), dim3(256), 0, stream>>>(x, gW, gb, tok_e, tok_g, counts, P_acc);
    k2_offsets<<<dim3(1), dim3(64), 0, stream>>>(counts, offs, mtile_e, P_acc,
                                                 out + (size_t)N_TOK * OUTD);
    k3_gather<<<dim3(N_TOK), dim3(256), 0, stream>>>(x, tok_e, tok_g, offs, cursor,
                                                     slot_token, slot_w, xg);
    k_conv<<<dim3(4096), dim3(256), 0, stream>>>((const float4*)W1, (ushort4*)Wbuf,
                                                 (int)((size_t)NEXP * HID * DIM / 4));
    moe_gemm<false><<<dim3(HID / 128, SLOT_TILES), dim3(256), 0, stream>>>(
        xg, Wbuf, b1, h, nullptr, mtile_e, slot_token, slot_w, DIM, HID);
    k_conv<<<dim3(4096), dim3(256), 0, stream>>>((const float4*)W2, (ushort4*)Wbuf,
                                                 (int)((size_t)NEXP * OUTD * HID / 4));
    moe_gemm<true><<<dim3(OUTD / 128, SLOT_TILES), dim3(256), 0, stream>>>(
        h, Wbuf, b2, nullptr, out, mtile_e, slot_token, slot_w, HID, OUTD);
}